// Round 1
// baseline (543.366 us; speedup 1.0000x reference)
//
#include <hip/hip_runtime.h>

// Problem constants (fixed by setup_inputs).
constexpr int L  = 512;   // sequence length
constexpr int CS = 384;   // c_s
constexpr int CH = 32;    // c_h
constexpr int CZ = 128;   // c_z
constexpr float LN_EPS = 1e-5f;

// ---------------------------------------------------------------------------
// Kernel 1: LayerNorm over c_s + dual projection (w1/b1, w2/b2) + mask.
// Writes a[512][32] and b[512][32] fp32 into workspace.
// block = 256 (4 waves), each wave handles one row; grid = L/4 = 128.
// ---------------------------------------------------------------------------
__global__ __launch_bounds__(256) void k_ln_proj(
    const float* __restrict__ s, const int* __restrict__ mask,
    const float* __restrict__ ln_scale, const float* __restrict__ ln_bias,
    const float* __restrict__ w1, const float* __restrict__ b1,
    const float* __restrict__ w2, const float* __restrict__ b2,
    float* __restrict__ a, float* __restrict__ b)
{
    __shared__ float sn_lds[4][CS];
    const int wave = threadIdx.x >> 6;
    const int lane = threadIdx.x & 63;
    const int row  = blockIdx.x * 4 + wave;

    const float* srow = s + row * CS;
    float v[6];
    float sum = 0.f, sumsq = 0.f;
#pragma unroll
    for (int q = 0; q < 6; ++q) {
        v[q] = srow[lane + 64 * q];
        sum   += v[q];
        sumsq += v[q] * v[q];
    }
#pragma unroll
    for (int off = 32; off; off >>= 1) {
        sum   += __shfl_xor(sum, off);
        sumsq += __shfl_xor(sumsq, off);
    }
    const float mu   = sum * (1.f / CS);
    const float var  = sumsq * (1.f / CS) - mu * mu;
    const float rstd = rsqrtf(var + LN_EPS);
#pragma unroll
    for (int q = 0; q < 6; ++q) {
        const int k = lane + 64 * q;
        sn_lds[wave][k] = (v[q] - mu) * rstd * ln_scale[k] + ln_bias[k];
    }
    __syncthreads();

    // Projection: lanes 0..31 -> a (w1,b1); lanes 32..63 -> b (w2,b2).
    const int c    = lane & 31;
    const int half = lane >> 5;
    const float* W  = half ? w2 : w1;
    const float* Bv = half ? b2 : b1;
    float acc = 0.f;
#pragma unroll 4
    for (int k = 0; k < CS; ++k)
        acc += sn_lds[wave][k] * W[k * CH + c];
    const float m = (float)mask[row];
    const float outv = (acc + Bv[c]) * m;
    (half ? b : a)[row * CH + c] = outv;
}

// ---------------------------------------------------------------------------
// Kernel 2: z[i,j,:] = a[i,:] @ T[j,:,:] + b_out, where
//           T[j][c][z] = sum_e b[j][e] * w_out[(c*32+e)*128 + z].
// grid = 512 (one block per j), block = 512 (8 waves).
// Phase A: build T[j] (32x128 f32, 16KB) in LDS cooperatively.
// Phase B: lane owns z-pair (2*lane, 2*lane+1); T column lives in 64 VGPRs.
//          Each wave streams 64 i-rows: uniform a-row loads + 64 FMA + one
//          float2 store per i (512B contiguous per wave -> fully coalesced).
// ---------------------------------------------------------------------------
__global__ __launch_bounds__(512, 4) void k_outer(
    const float* __restrict__ a, const float* __restrict__ b,
    const float* __restrict__ w_out, const float* __restrict__ b_out,
    float* __restrict__ out)
{
    __shared__ float T_lds[CH][CZ];   // 16 KB
    const int j = blockIdx.x;
    const int t = threadIdx.x;

    // ---- Phase A: T[c][z] for this j ----
    {
        float bj[CH];
#pragma unroll
        for (int e = 0; e < CH; ++e) bj[e] = b[j * CH + e];
        const int z  = t & (CZ - 1);
        const int c0 = (t >> 7) * 8;
#pragma unroll
        for (int cc = 0; cc < 8; ++cc) {
            const int c = c0 + cc;
            const float* wp = w_out + (size_t)(c * CH) * CZ + z;
            float acc = 0.f;
#pragma unroll
            for (int e = 0; e < CH; ++e)
                acc += bj[e] * wp[e * CZ];
            T_lds[c][z] = acc;
        }
    }
    __syncthreads();

    // ---- Phase B ----
    const int wave = t >> 6;
    const int lane = t & 63;

    float2 T_reg[CH];
#pragma unroll
    for (int c = 0; c < CH; ++c)
        T_reg[c] = *(const float2*)&T_lds[c][2 * lane];

    const float2 bo = *(const float2*)&b_out[2 * lane];
    float* outj = out + (size_t)j * CZ + (size_t)(2 * lane);

    const int i0 = wave * 64;
#pragma unroll 2
    for (int ii = 0; ii < 64; ++ii) {
        const int i = i0 + ii;
        const float* ar = a + i * CH;
        float av[CH];
#pragma unroll
        for (int q = 0; q < 8; ++q) {
            const float4 tmp = ((const float4*)ar)[q];
            av[4 * q + 0] = tmp.x;
            av[4 * q + 1] = tmp.y;
            av[4 * q + 2] = tmp.z;
            av[4 * q + 3] = tmp.w;
        }
        float ax = 0.f, ay = 0.f;
#pragma unroll
        for (int c = 0; c < CH; ++c) {
            ax += av[c] * T_reg[c].x;
            ay += av[c] * T_reg[c].y;
        }
        float2 o;
        o.x = ax + bo.x;
        o.y = ay + bo.y;
        *(float2*)(outj + (size_t)i * L * CZ) = o;
    }
}

// ---------------------------------------------------------------------------
extern "C" void kernel_launch(void* const* d_in, const int* in_sizes, int n_in,
                              void* d_out, int out_size, void* d_ws, size_t ws_size,
                              hipStream_t stream) {
    const float* s        = (const float*)d_in[0];
    const int*   mask     = (const int*)d_in[1];
    const float* ln_scale = (const float*)d_in[2];
    const float* ln_bias  = (const float*)d_in[3];
    const float* w1       = (const float*)d_in[4];
    const float* b1       = (const float*)d_in[5];
    const float* w2       = (const float*)d_in[6];
    const float* b2       = (const float*)d_in[7];
    const float* w_out    = (const float*)d_in[8];
    const float* b_out    = (const float*)d_in[9];
    float* out = (float*)d_out;

    // Workspace: a [512*32] f32, then b [512*32] f32 (128 KB total).
    float* a = (float*)d_ws;
    float* b = a + L * CH;

    k_ln_proj<<<L / 4, 256, 0, stream>>>(s, mask, ln_scale, ln_bias,
                                         w1, b1, w2, b2, a, b);
    k_outer<<<L, 512, 0, stream>>>(a, b, w_out, b_out, out);
}

// Round 2
// 206.078 us; speedup vs baseline: 2.6367x; 2.6367x over previous
//
#include <hip/hip_runtime.h>

// Problem constants (fixed by setup_inputs).
constexpr int L  = 512;   // sequence length
constexpr int CS = 384;   // c_s
constexpr int CH = 32;    // c_h
constexpr int CZ = 128;   // c_z
constexpr float LN_EPS = 1e-5f;

typedef float f2 __attribute__((ext_vector_type(2)));

// ---------------------------------------------------------------------------
// Kernel 1: LayerNorm over c_s + dual projection (w1/b1, w2/b2) + mask.
// Writes a[512][32] and b[512][32] fp32 into workspace.
// block = 256 (4 waves), each wave handles one row; grid = L/4 = 128.
// ---------------------------------------------------------------------------
__global__ __launch_bounds__(256) void k_ln_proj(
    const float* __restrict__ s, const int* __restrict__ mask,
    const float* __restrict__ ln_scale, const float* __restrict__ ln_bias,
    const float* __restrict__ w1, const float* __restrict__ b1,
    const float* __restrict__ w2, const float* __restrict__ b2,
    float* __restrict__ a, float* __restrict__ b)
{
    __shared__ float sn_lds[4][CS];
    const int wave = threadIdx.x >> 6;
    const int lane = threadIdx.x & 63;
    const int row  = blockIdx.x * 4 + wave;

    const float* srow = s + row * CS;
    float v[6];
    float sum = 0.f, sumsq = 0.f;
#pragma unroll
    for (int q = 0; q < 6; ++q) {
        v[q] = srow[lane + 64 * q];
        sum   += v[q];
        sumsq += v[q] * v[q];
    }
#pragma unroll
    for (int off = 32; off; off >>= 1) {
        sum   += __shfl_xor(sum, off);
        sumsq += __shfl_xor(sumsq, off);
    }
    const float mu   = sum * (1.f / CS);
    const float var  = sumsq * (1.f / CS) - mu * mu;
    const float rstd = rsqrtf(var + LN_EPS);
#pragma unroll
    for (int q = 0; q < 6; ++q) {
        const int k = lane + 64 * q;
        sn_lds[wave][k] = (v[q] - mu) * rstd * ln_scale[k] + ln_bias[k];
    }
    __syncthreads();

    // Projection: lanes 0..31 -> a (w1,b1); lanes 32..63 -> b (w2,b2).
    const int c    = lane & 31;
    const int half = lane >> 5;
    const float* W  = half ? w2 : w1;
    const float* Bv = half ? b2 : b1;
    float acc = 0.f;
#pragma unroll 4
    for (int k = 0; k < CS; ++k)
        acc += sn_lds[wave][k] * W[k * CH + c];
    const float m = (float)mask[row];
    const float outv = (acc + Bv[c]) * m;
    (half ? b : a)[row * CH + c] = outv;
}

// ---------------------------------------------------------------------------
// Kernel 2: T[j][c][z] = sum_e b[j][e] * w_out[(c*CH+e)*CZ + z]  (8 MB in ws).
// grid = 64 blocks x 512 threads; each block computes 8 j's and reads w_out
// exactly once (w_out total L2 demand = 32 MB instead of round-1's 268 MB).
// ---------------------------------------------------------------------------
__global__ __launch_bounds__(512) void k_T(
    const float* __restrict__ b, const float* __restrict__ w_out,
    float* __restrict__ T)
{
    const int t     = threadIdx.x;
    const int jbase = blockIdx.x * 8;
    const int z     = t & (CZ - 1);
    const int cgrp  = t >> 7;          // 0..3 -> c block of 8

    __shared__ float b_lds[8][CH];
    if (t < 8 * CH) ((float*)b_lds)[t] = b[jbase * CH + t];
    __syncthreads();

#pragma unroll
    for (int cc = 0; cc < 8; ++cc) {
        const int c = cgrp * 8 + cc;
        float w[CH];
        const float* wp = w_out + (size_t)(c * CH) * CZ + z;
#pragma unroll
        for (int e = 0; e < CH; ++e) w[e] = wp[e * CZ];
#pragma unroll
        for (int jj = 0; jj < 8; ++jj) {
            float acc = 0.f;
#pragma unroll
            for (int e = 0; e < CH; ++e) acc += b_lds[jj][e] * w[e];
            T[(size_t)(jbase + jj) * (CH * CZ) + c * CZ + z] = acc;
        }
    }
}

// ---------------------------------------------------------------------------
// Kernel 3: z[i,j,:] = a[i,:] @ T[j,:,:] + b_out.
// grid = 512: bj = bid & 63 (j-tile of 8), bi = bid >> 6 (i-tile of 64).
//   -> XCD x gets j-tiles {x, x+8, ...}: 1 MB of T per XCD, reused 8x.
// block = 512 (8 waves): wave owns j = j0 + wave, T[j] in 64 VGPRs (reused
// 64x); a-tile (8 KB) staged in LDS, rows read via broadcast ds_read_b128.
// Stores are nontemporal (no L2 allocation / RFO), all waves walk the same
// ii so the block's stores cluster into ~4 KB contiguous chunks.
// ---------------------------------------------------------------------------
__global__ __launch_bounds__(512) void k_main(
    const float* __restrict__ a, const float* __restrict__ T,
    const float* __restrict__ b_out, float* __restrict__ out)
{
    __shared__ float a_lds[64][CH];    // 8 KB

    const int bid = blockIdx.x;
    const int j0  = (bid & 63) * 8;
    const int i0  = (bid >> 6) * 64;
    const int t   = threadIdx.x;
    const int wave = t >> 6;
    const int lane = t & 63;
    const int j    = j0 + wave;

    // Stage a-tile: 2048 floats, 512 threads x float4.
    ((float4*)a_lds)[t] = ((const float4*)(a + (size_t)i0 * CH))[t];

    // T[j] column pair for this lane: 64 VGPRs.
    float2 T_reg[CH];
    const float* Tj = T + (size_t)j * (CH * CZ) + 2 * lane;
#pragma unroll
    for (int c = 0; c < CH; ++c)
        T_reg[c] = *(const float2*)(Tj + c * CZ);

    const float2 bo = *(const float2*)&b_out[2 * lane];
    float* outp = out + (size_t)i0 * L * CZ + (size_t)j * CZ + 2 * lane;

    __syncthreads();

#pragma unroll 2
    for (int ii = 0; ii < 64; ++ii) {
        const float4* ap = (const float4*)&a_lds[ii][0];
        float av[CH];
#pragma unroll
        for (int q = 0; q < 8; ++q) {
            const float4 tmp = ap[q];
            av[4 * q + 0] = tmp.x;
            av[4 * q + 1] = tmp.y;
            av[4 * q + 2] = tmp.z;
            av[4 * q + 3] = tmp.w;
        }
        float ax = 0.f, ay = 0.f;
#pragma unroll
        for (int c = 0; c < CH; ++c) {
            ax += av[c] * T_reg[c].x;
            ay += av[c] * T_reg[c].y;
        }
        f2 o;
        o.x = ax + bo.x;
        o.y = ay + bo.y;
        __builtin_nontemporal_store(o, (f2*)(outp + (size_t)ii * L * CZ));
    }
}

// ---------------------------------------------------------------------------
extern "C" void kernel_launch(void* const* d_in, const int* in_sizes, int n_in,
                              void* d_out, int out_size, void* d_ws, size_t ws_size,
                              hipStream_t stream) {
    const float* s        = (const float*)d_in[0];
    const int*   mask     = (const int*)d_in[1];
    const float* ln_scale = (const float*)d_in[2];
    const float* ln_bias  = (const float*)d_in[3];
    const float* w1       = (const float*)d_in[4];
    const float* b1       = (const float*)d_in[5];
    const float* w2       = (const float*)d_in[6];
    const float* b2       = (const float*)d_in[7];
    const float* w_out    = (const float*)d_in[8];
    const float* b_out    = (const float*)d_in[9];
    float* out = (float*)d_out;

    // Workspace: a [512*32], b [512*32], T [512*32*128]  (8.125 MB total).
    float* a = (float*)d_ws;
    float* b = a + L * CH;
    float* T = b + L * CH;

    k_ln_proj<<<L / 4, 256, 0, stream>>>(s, mask, ln_scale, ln_bias,
                                         w1, b1, w2, b2, a, b);
    k_T<<<L / 8, 512, 0, stream>>>(b, w_out, T);
    k_main<<<512, 512, 0, stream>>>(a, T, b_out, out);
}

// Round 3
// 84.290 us; speedup vs baseline: 6.4464x; 2.4449x over previous
//
#include <hip/hip_runtime.h>

// Problem constants (fixed by setup_inputs).
constexpr int L  = 512;   // sequence length
constexpr int CS = 384;   // c_s
constexpr int CH = 32;    // c_h
constexpr int CZ = 128;   // c_z
constexpr float LN_EPS = 1e-5f;

typedef float f2 __attribute__((ext_vector_type(2)));

// ---------------------------------------------------------------------------
// Kernel 1: LayerNorm over c_s + dual projection (w1/b1, w2/b2) + mask.
// Writes a[512][32] and b[512][32] fp32 into workspace.
// block = 256 (4 waves), each wave handles one row; grid = L/4 = 128.
// ---------------------------------------------------------------------------
__global__ __launch_bounds__(256) void k_ln_proj(
    const float* __restrict__ s, const int* __restrict__ mask,
    const float* __restrict__ ln_scale, const float* __restrict__ ln_bias,
    const float* __restrict__ w1, const float* __restrict__ b1,
    const float* __restrict__ w2, const float* __restrict__ b2,
    float* __restrict__ a, float* __restrict__ b)
{
    __shared__ float sn_lds[4][CS];
    const int wave = threadIdx.x >> 6;
    const int lane = threadIdx.x & 63;
    const int row  = blockIdx.x * 4 + wave;

    const float* srow = s + row * CS;
    float v[6];
    float sum = 0.f, sumsq = 0.f;
#pragma unroll
    for (int q = 0; q < 6; ++q) {
        v[q] = srow[lane + 64 * q];
        sum   += v[q];
        sumsq += v[q] * v[q];
    }
#pragma unroll
    for (int off = 32; off; off >>= 1) {
        sum   += __shfl_xor(sum, off);
        sumsq += __shfl_xor(sumsq, off);
    }
    const float mu   = sum * (1.f / CS);
    const float var  = sumsq * (1.f / CS) - mu * mu;
    const float rstd = rsqrtf(var + LN_EPS);
#pragma unroll
    for (int q = 0; q < 6; ++q) {
        const int k = lane + 64 * q;
        sn_lds[wave][k] = (v[q] - mu) * rstd * ln_scale[k] + ln_bias[k];
    }
    __syncthreads();

    // Projection: lanes 0..31 -> a (w1,b1); lanes 32..63 -> b (w2,b2).
    const int c    = lane & 31;
    const int half = lane >> 5;
    const float* W  = half ? w2 : w1;
    const float* Bv = half ? b2 : b1;
    float acc = 0.f;
#pragma unroll 4
    for (int k = 0; k < CS; ++k)
        acc += sn_lds[wave][k] * W[k * CH + c];
    const float m = (float)mask[row];
    const float outv = (acc + Bv[c]) * m;
    (half ? b : a)[row * CH + c] = outv;
}

// ---------------------------------------------------------------------------
// Kernel 2: T[j][c][z] = sum_e b[j][e] * w_out[(c*CH+e)*CZ + z]  (8 MB in ws).
// Spill-free layout: each thread owns ONE (c,z) pair -> w[32] loaded once
// (32 VGPRs), loops over a 64-row j-chunk staged in LDS.
// grid = 8 (c,z)-slices x 8 j-groups = 64 blocks x 512 threads.
// w_out total read = 8 x 512 KB = 4 MB L2 demand; stores lane-contiguous.
// ---------------------------------------------------------------------------
__global__ __launch_bounds__(512) void k_T(
    const float* __restrict__ b, const float* __restrict__ w_out,
    float* __restrict__ T)
{
    const int czg = blockIdx.x & 7;    // (c,z) slice: 512 pairs
    const int jg  = blockIdx.x >> 3;   // j-chunk of 64
    const int t   = threadIdx.x;
    const int idx = czg * 512 + t;     // linear (c,z): c = idx>>7, z = idx&127
    const int c   = idx >> 7;
    const int z   = idx & (CZ - 1);

    float w[CH];
    const float* wp = w_out + (size_t)(c * CH) * CZ + z;
#pragma unroll
    for (int e = 0; e < CH; ++e) w[e] = wp[e * CZ];

    __shared__ float b_lds[64][CH];    // 8 KB
    ((float4*)b_lds)[t] = ((const float4*)(b + (size_t)jg * 64 * CH))[t];
    __syncthreads();

    float* Tp = T + (size_t)(jg * 64) * (CH * CZ) + idx;
#pragma unroll 4
    for (int jj = 0; jj < 64; ++jj) {
        float acc = 0.f;
#pragma unroll
        for (int e = 0; e < CH; ++e) acc += b_lds[jj][e] * w[e];
        Tp[(size_t)jj * (CH * CZ)] = acc;
    }
}

// ---------------------------------------------------------------------------
// Kernel 3: z[i,j,:] = a[i,:] @ T[j,:,:] + b_out.
// grid = 512: bj = bid & 63 (j-tile of 8), bi = bid >> 6 (i-tile of 64).
//   -> XCD x gets j-tiles {x, x+8, ...}: 1 MB of T per XCD, reused 8x.
// block = 512 (8 waves): wave owns j = j0 + wave, T[j] in 64 VGPRs (reused
// 64x); a-tile (8 KB) staged in LDS, rows read via broadcast ds_read_b128.
// Stores are nontemporal (no L2 allocation / RFO), all waves walk the same
// ii so the block's stores cluster into ~4 KB contiguous chunks.
// ---------------------------------------------------------------------------
__global__ __launch_bounds__(512) void k_main(
    const float* __restrict__ a, const float* __restrict__ T,
    const float* __restrict__ b_out, float* __restrict__ out)
{
    __shared__ float a_lds[64][CH];    // 8 KB

    const int bid = blockIdx.x;
    const int j0  = (bid & 63) * 8;
    const int i0  = (bid >> 6) * 64;
    const int t   = threadIdx.x;
    const int wave = t >> 6;
    const int lane = t & 63;
    const int j    = j0 + wave;

    // Stage a-tile: 2048 floats, 512 threads x float4.
    ((float4*)a_lds)[t] = ((const float4*)(a + (size_t)i0 * CH))[t];

    // T[j] column pair for this lane: 64 VGPRs.
    float2 T_reg[CH];
    const float* Tj = T + (size_t)j * (CH * CZ) + 2 * lane;
#pragma unroll
    for (int c = 0; c < CH; ++c)
        T_reg[c] = *(const float2*)(Tj + c * CZ);

    const float2 bo = *(const float2*)&b_out[2 * lane];
    float* outp = out + (size_t)i0 * L * CZ + (size_t)j * CZ + 2 * lane;

    __syncthreads();

#pragma unroll 2
    for (int ii = 0; ii < 64; ++ii) {
        const float4* ap = (const float4*)&a_lds[ii][0];
        float av[CH];
#pragma unroll
        for (int q = 0; q < 8; ++q) {
            const float4 tmp = ap[q];
            av[4 * q + 0] = tmp.x;
            av[4 * q + 1] = tmp.y;
            av[4 * q + 2] = tmp.z;
            av[4 * q + 3] = tmp.w;
        }
        float ax = 0.f, ay = 0.f;
#pragma unroll
        for (int c = 0; c < CH; ++c) {
            ax += av[c] * T_reg[c].x;
            ay += av[c] * T_reg[c].y;
        }
        f2 o;
        o.x = ax + bo.x;
        o.y = ay + bo.y;
        __builtin_nontemporal_store(o, (f2*)(outp + (size_t)ii * L * CZ));
    }
}

// ---------------------------------------------------------------------------
extern "C" void kernel_launch(void* const* d_in, const int* in_sizes, int n_in,
                              void* d_out, int out_size, void* d_ws, size_t ws_size,
                              hipStream_t stream) {
    const float* s        = (const float*)d_in[0];
    const int*   mask     = (const int*)d_in[1];
    const float* ln_scale = (const float*)d_in[2];
    const float* ln_bias  = (const float*)d_in[3];
    const float* w1       = (const float*)d_in[4];
    const float* b1       = (const float*)d_in[5];
    const float* w2       = (const float*)d_in[6];
    const float* b2       = (const float*)d_in[7];
    const float* w_out    = (const float*)d_in[8];
    const float* b_out    = (const float*)d_in[9];
    float* out = (float*)d_out;

    // Workspace: a [512*32], b [512*32], T [512*32*128]  (8.125 MB total).
    float* a = (float*)d_ws;
    float* b = a + L * CH;
    float* T = b + L * CH;

    k_ln_proj<<<L / 4, 256, 0, stream>>>(s, mask, ln_scale, ln_bias,
                                         w1, b1, w2, b2, a, b);
    k_T<<<L / 8, 512, 0, stream>>>(b, w_out, T);
    k_main<<<512, 512, 0, stream>>>(a, T, b_out, out);
}